// Round 7
// baseline (1444.509 us; speedup 1.0000x reference)
//
#include <hip/hip_runtime.h>
#include <hip/hip_bf16.h>

// Problem constants
#define BN_NODES 4096      // B*N = 8*512
#define KNN 16
#define C_POOL 256
#define G_DIM 128
#define IN_DIM 384         // C_POOL + G_DIM
#define L_DIM 512
#define OUT_STRIDE 1920    // 384 + 3*512

#define X1_OFF 384
#define X2_OFF 896
#define X3_OFF 1408

#define NBLK 512           // grid size; 2 blocks/CU co-resident (launch_bounds)

typedef __attribute__((ext_vector_type(8))) __bf16 bf16x8;
typedef __attribute__((ext_vector_type(4))) float floatx4;

static __device__ __forceinline__ ushort f2bf(float v) {
  return __builtin_bit_cast(ushort, __float2bfloat16(v));
}
static __device__ __forceinline__ float bf2f(ushort u) {
  return __builtin_bit_cast(float, ((unsigned)u) << 16);
}
static __device__ __forceinline__ void gld_lds(const ushort* g, ushort* l) {
  __builtin_amdgcn_global_load_lds(
      (const __attribute__((address_space(1))) void*)g,
      (__attribute__((address_space(3))) void*)l, 16, 0, 0);
}

// Software grid barrier (monotone counter). All NBLK blocks co-resident by
// occupancy arithmetic (2 blocks/CU x 256 CU, enforced via launch_bounds).
// Device-scope fences per G16 for cross-XCD visibility of normal stores.
static __device__ __forceinline__ void gbar(unsigned* c, unsigned target) {
  __threadfence();          // publish this thread's stores (agent scope)
  __syncthreads();
  if (threadIdx.x == 0) {
    __hip_atomic_fetch_add(c, 1u, __ATOMIC_ACQ_REL, __HIP_MEMORY_SCOPE_AGENT);
    while (__hip_atomic_load(c, __ATOMIC_ACQUIRE, __HIP_MEMORY_SCOPE_AGENT) <
           target) {
      __builtin_amdgcn_s_sleep(1);
    }
  }
  __syncthreads();
  __threadfence();          // acquire: invalidate stale L1/L2 before reads
}

// ---------------------------------------------------------------------------
// Mega kernel: prep -> 3 x (PQ GEMM -> bar -> edge max -> bar). One dispatch.
// 512 blocks x 512 threads, 24 KB LDS (GEMM phase), <=128 VGPR.
// ---------------------------------------------------------------------------
__global__ __launch_bounds__(512, 4) void mega_kernel(
    const float* __restrict__ rois, const float* __restrict__ pooled,
    const float* __restrict__ gW1, const float* __restrict__ gb1,
    const float* __restrict__ gW2, const float* __restrict__ gb2,
    const float* __restrict__ W0, const float* __restrict__ W1,
    const float* __restrict__ W2, const float* __restrict__ fb0,
    const float* __restrict__ fb1, const float* __restrict__ fb2,
    const int* __restrict__ src, float* __restrict__ out,
    ushort* __restrict__ Xb, ushort* __restrict__ Wb0,
    ushort* __restrict__ Wb1, ushort* __restrict__ Wb2,
    ushort* __restrict__ PQb, unsigned* __restrict__ bar) {
  __shared__ __align__(16) ushort smem[12288];  // 24 KB, re-used per phase
  const int blk = blockIdx.x;
  const int tid = threadIdx.x;

  // ================= phase 0: prep =================
  if (blk < 256) {
    // ---- node_feat: 16 nodes per block ----
    float* h1 = (float*)smem;                    // 16*128 floats = 8 KB
    float* rs = (float*)smem + 16 * G_DIM;       // 112 floats
    const int nb = blk * 16;
    const int c = tid & 127;
    const int nh = tid >> 7;  // 0..3, each handles 4 nodes
    if (tid < 112) rs[tid] = rois[(size_t)nb * 7 + tid];
    __syncthreads();
    {
      float w1[7];
#pragma unroll
      for (int i = 0; i < 7; i++) w1[i] = gW1[c * 7 + i];
      float b1v = gb1[c];
#pragma unroll
      for (int n = 0; n < 4; n++) {
        int nl = nh * 4 + n;
        float a = b1v;
#pragma unroll
        for (int i = 0; i < 7; i++) a += rs[nl * 7 + i] * w1[i];
        h1[nl * G_DIM + c] = fmaxf(a, 0.f);
      }
    }
    __syncthreads();
    float acc[4];
    {
      float b2v = gb2[c];
#pragma unroll
      for (int n = 0; n < 4; n++) acc[n] = b2v;
      const float4* w4 = (const float4*)(gW2 + (size_t)c * G_DIM);
#pragma unroll 4
      for (int kc4 = 0; kc4 < G_DIM / 4; kc4++) {
        float4 wv = w4[kc4];
#pragma unroll
        for (int n = 0; n < 4; n++) {
          float4 hv = ((const float4*)&h1[(nh * 4 + n) * G_DIM])[kc4];
          acc[n] += wv.x * hv.x + wv.y * hv.y + wv.z * hv.z + wv.w * hv.w;
        }
      }
    }
#pragma unroll
    for (int n = 0; n < 4; n++) {
      int node = nb + nh * 4 + n;
      float g = fmaxf(acc[n], 0.f);
      const float* prow = pooled + (size_t)node * C_POOL;
      float p0 = prow[c], p1 = prow[G_DIM + c];
      float* orow = out + (size_t)node * OUT_STRIDE;
      orow[c] = p0;
      orow[G_DIM + c] = p1;
      orow[C_POOL + c] = g;
      ushort* xrow = Xb + (size_t)node * IN_DIM;
      xrow[c] = f2bf(p0);
      xrow[G_DIM + c] = f2bf(p1);
      xrow[C_POOL + c] = f2bf(g);
    }
  } else {
    // ---- wconv: Wb_l[j][k] = (j<512) ? W[j][k] : W[j-512][K+k] ----
    // concatenated ushort4 space: Wb0 393216, Wb1 524288, Wb2 524288 elems
    int idx = (blk - 256) * 512 + tid;
    for (; idx < 360448; idx += 131072) {
      int e4 = idx * 4;
      const float* W;
      ushort* Wb;
      int j, k, K;
      if (e4 < 393216) {
        K = IN_DIM; W = W0; Wb = Wb0;
        j = e4 / 384; k = e4 - j * 384;
      } else if (e4 < 917504) {
        int o = e4 - 393216;
        K = L_DIM; W = W1; Wb = Wb1;
        j = o >> 9; k = o & 511;
      } else {
        int o = e4 - 917504;
        K = L_DIM; W = W2; Wb = Wb2;
        j = o >> 9; k = o & 511;
      }
      const float* sp = (j < 512) ? W + (size_t)j * (2 * K) + k
                                  : W + (size_t)(j - 512) * (2 * K) + K + k;
      ushort4 pk;
      pk.x = f2bf(sp[0]);
      pk.y = f2bf(sp[1]);
      pk.z = f2bf(sp[2]);
      pk.w = f2bf(sp[3]);
      *(ushort4*)(Wb + (size_t)j * K + k) = pk;
    }
  }

  unsigned gen = 0;
  gbar(bar, ++gen * NBLK);

  // ================= 3 layers =================
  for (int l = 0; l < 3; l++) {
    const int K = (l == 0) ? IN_DIM : L_DIM;
    const ushort* Wbp = (l == 0) ? Wb0 : (l == 1) ? Wb1 : Wb2;
    const float* bias = (l == 0) ? fb0 : (l == 1) ? fb1 : fb2;
    const int out_off = (l == 0) ? X1_OFF : (l == 1) ? X2_OFF : X3_OFF;

    // ---- GEMM: PQb[4096x1024] = Xb[4096xK] @ Wbp[1024xK]^T ----
    // tile 128x64, BK=64, 8 waves (4x2), wave 32x32; fragment-order LDS.
    {
      ushort* sA = smem;          // 8192 ushorts = 16 KB (16 tiles)
      ushort* sB = smem + 8192;   // 4096 ushorts =  8 KB (8 tiles)
      const int lane = tid & 63;
      const int w = tid >> 6;
      const int wm = w >> 1, wn = w & 1;
      const int fr = lane & 15;
      const int kc = lane >> 4;
      const int bm = blk >> 4, bn = blk & 15;
      floatx4 acc[2][2];
#pragma unroll
      for (int i = 0; i < 2; i++)
#pragma unroll
        for (int j = 0; j < 2; j++) acc[i][j] = (floatx4){0.f, 0.f, 0.f, 0.f};

      for (int k0 = 0; k0 < K; k0 += 64) {
#pragma unroll
        for (int r = 0; r < 2; r++) {
          int ta = w + r * 8;
          int rt = ta >> 1, ks = ta & 1;
          const ushort* ga =
              Xb + (size_t)(bm * 128 + rt * 16 + fr) * K + k0 + ks * 32 + kc * 8;
          gld_lds(ga, &sA[ta * 512 + lane * 8]);
        }
        {
          int ct = w >> 1, ks = w & 1;
          const ushort* gb =
              Wbp + (size_t)(bn * 64 + ct * 16 + fr) * K + k0 + ks * 32 + kc * 8;
          gld_lds(gb, &sB[w * 512 + lane * 8]);
        }
        __syncthreads();
#pragma unroll
        for (int ks = 0; ks < 2; ks++) {
          bf16x8 af[2], bf[2];
#pragma unroll
          for (int i = 0; i < 2; i++)
            af[i] =
                *(const bf16x8*)&sA[((wm * 2 + i) * 2 + ks) * 512 + lane * 8];
#pragma unroll
          for (int j = 0; j < 2; j++)
            bf[j] =
                *(const bf16x8*)&sB[((wn * 2 + j) * 2 + ks) * 512 + lane * 8];
#pragma unroll
          for (int i = 0; i < 2; i++)
#pragma unroll
            for (int j = 0; j < 2; j++)
              acc[i][j] = __builtin_amdgcn_mfma_f32_16x16x32_bf16(
                  af[i], bf[j], acc[i][j], 0, 0, 0);
        }
        __syncthreads();
      }
      // C/D layout: col = fr, row = kc*4 + reg (m89-verified)
      const int rowB = bm * 128 + wm * 32 + kc * 4;
      const int colB = bn * 64 + wn * 32 + fr;
#pragma unroll
      for (int i = 0; i < 2; i++)
#pragma unroll
        for (int j = 0; j < 2; j++)
#pragma unroll
          for (int r = 0; r < 4; r++)
            PQb[(size_t)(rowB + i * 16 + r) * 1024 + colB + j * 16] =
                f2bf(acc[i][j][r]);
    }

    gbar(bar, ++gen * NBLK);

    // ---- edge: 8 nodes per block ----
    {
      int* s = (int*)smem;  // 8*16 ints
      if (tid < 128) s[tid] = src[(size_t)(blk * 8) * KNN + tid];
      __syncthreads();
      const int sub = tid & 127;   // float4 channel group
      const int ng = tid >> 7;     // 0..3
      const float4 bb = *(const float4*)&bias[sub * 4];
#pragma unroll
      for (int it = 0; it < 2; it++) {
        int nl = ng + it * 4;
        int n = blk * 8 + nl;
        float mx = -1e30f, my = -1e30f, mz = -1e30f, mw = -1e30f;
#pragma unroll
        for (int k = 0; k < KNN; k++) {
          int sa = s[nl * KNN + k];
          ushort4 u = *(const ushort4*)(PQb + (size_t)sa * 1024 + sub * 4);
          mx = fmaxf(mx, bf2f(u.x));
          my = fmaxf(my, bf2f(u.y));
          mz = fmaxf(mz, bf2f(u.z));
          mw = fmaxf(mw, bf2f(u.w));
        }
        const ushort* row = PQb + (size_t)n * 1024;
        ushort4 pu = *(const ushort4*)(row + sub * 4);
        ushort4 qu = *(const ushort4*)(row + 512 + sub * 4);
        float4 res;
        res.x = fmaxf(mx - bf2f(pu.x) + bf2f(qu.x) + bb.x, 0.f);
        res.y = fmaxf(my - bf2f(pu.y) + bf2f(qu.y) + bb.y, 0.f);
        res.z = fmaxf(mz - bf2f(pu.z) + bf2f(qu.z) + bb.z, 0.f);
        res.w = fmaxf(mw - bf2f(pu.w) + bf2f(qu.w) + bb.w, 0.f);
        *(float4*)(out + (size_t)n * OUT_STRIDE + out_off + sub * 4) = res;
        if (l < 2) {
          ushort4 pk;
          pk.x = f2bf(res.x);
          pk.y = f2bf(res.y);
          pk.z = f2bf(res.z);
          pk.w = f2bf(res.w);
          *(ushort4*)(Xb + (size_t)n * L_DIM + sub * 4) = pk;
        }
      }
    }

    if (l < 2) gbar(bar, ++gen * NBLK);
  }
}

extern "C" void kernel_launch(void* const* d_in, const int* in_sizes, int n_in,
                              void* d_out, int out_size, void* d_ws,
                              size_t ws_size, hipStream_t stream) {
  const float* rois = (const float*)d_in[0];
  const float* pooled = (const float*)d_in[1];
  const int* edge_index = (const int*)d_in[2];
  const float* gW1 = (const float*)d_in[3];
  const float* gb1 = (const float*)d_in[4];
  const float* gW2 = (const float*)d_in[5];
  const float* gb2 = (const float*)d_in[6];
  const float* fcW0 = (const float*)d_in[7];
  const float* fcb0 = (const float*)d_in[8];
  const float* fcW1 = (const float*)d_in[9];
  const float* fcb1 = (const float*)d_in[10];
  const float* fcW2 = (const float*)d_in[11];
  const float* fcb2 = (const float*)d_in[12];
  float* out = (float*)d_out;
  const int* src = edge_index;  // dst[e] == e/16 by construction

  // workspace layout (bytes):
  //   PQb : 4096*1024 bf16 = 8 MB  @ 0
  //   Xb  : 4096*512  bf16 = 4 MB  @ 8 MB  (stride IN_DIM for x0, L_DIM after)
  //   Wb0 : 1024*384  bf16         @ 12 MB
  //   Wb1 : 1024*512  bf16         @ 13 MB
  //   Wb2 : 1024*512  bf16         @ 14 MB
  //   bar : 64 B                   @ 16 MB
  char* ws = (char*)d_ws;
  ushort* PQb = (ushort*)ws;
  ushort* Xb = (ushort*)(ws + (size_t)8 * 1024 * 1024);
  ushort* Wb0 = (ushort*)(ws + (size_t)12 * 1024 * 1024);
  ushort* Wb1 = (ushort*)(ws + (size_t)13 * 1024 * 1024);
  ushort* Wb2 = (ushort*)(ws + (size_t)14 * 1024 * 1024);
  unsigned* bar = (unsigned*)(ws + (size_t)16 * 1024 * 1024);

  hipMemsetAsync(bar, 0, 64, stream);
  mega_kernel<<<NBLK, 512, 0, stream>>>(rois, pooled, gW1, gb1, gW2, gb2, fcW0,
                                        fcW1, fcW2, fcb0, fcb1, fcb2, src, out,
                                        Xb, Wb0, Wb1, Wb2, PQb, bar);
}

// Round 8
// 799.425 us; speedup vs baseline: 1.8069x; 1.8069x over previous
//
#include <hip/hip_runtime.h>
#include <hip/hip_bf16.h>

// Problem constants
#define BN_NODES 4096      // B*N = 8*512
#define KNN 16
#define C_POOL 256
#define G_DIM 128
#define IN_DIM 384         // C_POOL + G_DIM
#define L_DIM 512
#define OUT_STRIDE 1920    // 384 + 3*512

#define X1_OFF 384
#define X2_OFF 896
#define X3_OFF 1408

#define NBLK 512           // grid size; 2 blocks/CU co-resident (launch_bounds)

typedef __attribute__((ext_vector_type(8))) __bf16 bf16x8;
typedef __attribute__((ext_vector_type(4))) float floatx4;

static __device__ __forceinline__ ushort f2bf(float v) {
  return __builtin_bit_cast(ushort, __float2bfloat16(v));
}
static __device__ __forceinline__ float bf2f(ushort u) {
  return __builtin_bit_cast(float, ((unsigned)u) << 16);
}
static __device__ __forceinline__ void gld_lds(const ushort* g, ushort* l) {
  __builtin_amdgcn_global_load_lds(
      (const __attribute__((address_space(1))) void*)g,
      (__attribute__((address_space(3))) void*)l, 16, 0, 0);
}

// Software grid barrier. KEY FIX vs R7: poll with RELAXED loads (no cache op
// per iteration); one release fence before arrival, one acquire fence (all
// threads) after exit. R7's ACQUIRE-per-poll invalidated L1/L2 continuously
// -> 230 us/barrier, 101 MB overfetch.
static __device__ __forceinline__ void gbar(unsigned* c, unsigned target) {
  __syncthreads();
  if (threadIdx.x == 0) {
    __threadfence();  // release: publish this block's stores
    __hip_atomic_fetch_add(c, 1u, __ATOMIC_RELAXED, __HIP_MEMORY_SCOPE_AGENT);
    while (__hip_atomic_load(c, __ATOMIC_RELAXED, __HIP_MEMORY_SCOPE_AGENT) <
           target) {
      __builtin_amdgcn_s_sleep(2);
    }
  }
  __syncthreads();
  __threadfence();  // acquire once: invalidate stale caches before reads
}

// ---------------------------------------------------------------------------
// Mega kernel: prep -> 3 x (PQ GEMM -> bar -> edge max -> bar). One dispatch.
// 512 blocks x 512 threads, 24 KB LDS (GEMM phase), <=128 VGPR.
// ---------------------------------------------------------------------------
__global__ __launch_bounds__(512, 4) void mega_kernel(
    const float* __restrict__ rois, const float* __restrict__ pooled,
    const float* __restrict__ gW1, const float* __restrict__ gb1,
    const float* __restrict__ gW2, const float* __restrict__ gb2,
    const float* __restrict__ W0, const float* __restrict__ W1,
    const float* __restrict__ W2, const float* __restrict__ fb0,
    const float* __restrict__ fb1, const float* __restrict__ fb2,
    const int* __restrict__ src, float* __restrict__ out,
    ushort* __restrict__ Xb, ushort* __restrict__ Wb0,
    ushort* __restrict__ Wb1, ushort* __restrict__ Wb2,
    ushort* __restrict__ PQb, unsigned* __restrict__ bar) {
  __shared__ __align__(16) ushort smem[12288];  // 24 KB, re-used per phase
  const int blk = blockIdx.x;
  const int tid = threadIdx.x;

  // ================= phase 0: prep =================
  if (blk < 256) {
    // ---- node_feat: 16 nodes per block ----
    float* h1 = (float*)smem;                    // 16*128 floats = 8 KB
    float* rs = (float*)smem + 16 * G_DIM;       // 112 floats
    const int nb = blk * 16;
    const int c = tid & 127;
    const int nh = tid >> 7;  // 0..3, each handles 4 nodes
    if (tid < 112) rs[tid] = rois[(size_t)nb * 7 + tid];
    __syncthreads();
    {
      float w1[7];
#pragma unroll
      for (int i = 0; i < 7; i++) w1[i] = gW1[c * 7 + i];
      float b1v = gb1[c];
#pragma unroll
      for (int n = 0; n < 4; n++) {
        int nl = nh * 4 + n;
        float a = b1v;
#pragma unroll
        for (int i = 0; i < 7; i++) a += rs[nl * 7 + i] * w1[i];
        h1[nl * G_DIM + c] = fmaxf(a, 0.f);
      }
    }
    __syncthreads();
    float acc[4];
    {
      float b2v = gb2[c];
#pragma unroll
      for (int n = 0; n < 4; n++) acc[n] = b2v;
      const float4* w4 = (const float4*)(gW2 + (size_t)c * G_DIM);
#pragma unroll 4
      for (int kc4 = 0; kc4 < G_DIM / 4; kc4++) {
        float4 wv = w4[kc4];
#pragma unroll
        for (int n = 0; n < 4; n++) {
          float4 hv = ((const float4*)&h1[(nh * 4 + n) * G_DIM])[kc4];
          acc[n] += wv.x * hv.x + wv.y * hv.y + wv.z * hv.z + wv.w * hv.w;
        }
      }
    }
#pragma unroll
    for (int n = 0; n < 4; n++) {
      int node = nb + nh * 4 + n;
      float g = fmaxf(acc[n], 0.f);
      const float* prow = pooled + (size_t)node * C_POOL;
      float p0 = prow[c], p1 = prow[G_DIM + c];
      float* orow = out + (size_t)node * OUT_STRIDE;
      orow[c] = p0;
      orow[G_DIM + c] = p1;
      orow[C_POOL + c] = g;
      ushort* xrow = Xb + (size_t)node * IN_DIM;
      xrow[c] = f2bf(p0);
      xrow[G_DIM + c] = f2bf(p1);
      xrow[C_POOL + c] = f2bf(g);
    }
  } else {
    // ---- wconv: Wb_l[j][k] = (j<512) ? W[j][k] : W[j-512][K+k] ----
    // concatenated ushort4 space: Wb0 393216, Wb1 524288, Wb2 524288 elems
    int idx = (blk - 256) * 512 + tid;
    for (; idx < 360448; idx += 131072) {
      int e4 = idx * 4;
      const float* W;
      ushort* Wb;
      int j, k, K;
      if (e4 < 393216) {
        K = IN_DIM; W = W0; Wb = Wb0;
        j = e4 / 384; k = e4 - j * 384;
      } else if (e4 < 917504) {
        int o = e4 - 393216;
        K = L_DIM; W = W1; Wb = Wb1;
        j = o >> 9; k = o & 511;
      } else {
        int o = e4 - 917504;
        K = L_DIM; W = W2; Wb = Wb2;
        j = o >> 9; k = o & 511;
      }
      const float* sp = (j < 512) ? W + (size_t)j * (2 * K) + k
                                  : W + (size_t)(j - 512) * (2 * K) + K + k;
      ushort4 pk;
      pk.x = f2bf(sp[0]);
      pk.y = f2bf(sp[1]);
      pk.z = f2bf(sp[2]);
      pk.w = f2bf(sp[3]);
      *(ushort4*)(Wb + (size_t)j * K + k) = pk;
    }
  }

  unsigned gen = 0;
  gbar(bar, ++gen * NBLK);

  // ================= 3 layers =================
  for (int l = 0; l < 3; l++) {
    const int K = (l == 0) ? IN_DIM : L_DIM;
    const ushort* Wbp = (l == 0) ? Wb0 : (l == 1) ? Wb1 : Wb2;
    const float* bias = (l == 0) ? fb0 : (l == 1) ? fb1 : fb2;
    const int out_off = (l == 0) ? X1_OFF : (l == 1) ? X2_OFF : X3_OFF;

    // ---- GEMM: PQb[4096x1024] = Xb[4096xK] @ Wbp[1024xK]^T ----
    // tile 128x64, BK=64, 8 waves (4x2), wave 32x32; fragment-order LDS.
    {
      ushort* sA = smem;          // 8192 ushorts = 16 KB (16 tiles)
      ushort* sB = smem + 8192;   // 4096 ushorts =  8 KB (8 tiles)
      const int lane = tid & 63;
      const int w = tid >> 6;
      const int wm = w >> 1, wn = w & 1;
      const int fr = lane & 15;
      const int kc = lane >> 4;
      const int bm = blk >> 4, bn = blk & 15;
      floatx4 acc[2][2];
#pragma unroll
      for (int i = 0; i < 2; i++)
#pragma unroll
        for (int j = 0; j < 2; j++) acc[i][j] = (floatx4){0.f, 0.f, 0.f, 0.f};

      for (int k0 = 0; k0 < K; k0 += 64) {
#pragma unroll
        for (int r = 0; r < 2; r++) {
          int ta = w + r * 8;
          int rt = ta >> 1, ks = ta & 1;
          const ushort* ga =
              Xb + (size_t)(bm * 128 + rt * 16 + fr) * K + k0 + ks * 32 + kc * 8;
          gld_lds(ga, &sA[ta * 512 + lane * 8]);
        }
        {
          int ct = w >> 1, ks = w & 1;
          const ushort* gb =
              Wbp + (size_t)(bn * 64 + ct * 16 + fr) * K + k0 + ks * 32 + kc * 8;
          gld_lds(gb, &sB[w * 512 + lane * 8]);
        }
        __syncthreads();
#pragma unroll
        for (int ks = 0; ks < 2; ks++) {
          bf16x8 af[2], bf[2];
#pragma unroll
          for (int i = 0; i < 2; i++)
            af[i] =
                *(const bf16x8*)&sA[((wm * 2 + i) * 2 + ks) * 512 + lane * 8];
#pragma unroll
          for (int j = 0; j < 2; j++)
            bf[j] =
                *(const bf16x8*)&sB[((wn * 2 + j) * 2 + ks) * 512 + lane * 8];
#pragma unroll
          for (int i = 0; i < 2; i++)
#pragma unroll
            for (int j = 0; j < 2; j++)
              acc[i][j] = __builtin_amdgcn_mfma_f32_16x16x32_bf16(
                  af[i], bf[j], acc[i][j], 0, 0, 0);
        }
        __syncthreads();
      }
      // C/D layout: col = fr, row = kc*4 + reg (m89-verified)
      const int rowB = bm * 128 + wm * 32 + kc * 4;
      const int colB = bn * 64 + wn * 32 + fr;
#pragma unroll
      for (int i = 0; i < 2; i++)
#pragma unroll
        for (int j = 0; j < 2; j++)
#pragma unroll
          for (int r = 0; r < 4; r++)
            PQb[(size_t)(rowB + i * 16 + r) * 1024 + colB + j * 16] =
                f2bf(acc[i][j][r]);
    }

    gbar(bar, ++gen * NBLK);

    // ---- edge: 8 nodes per block ----
    {
      int* s = (int*)smem;  // 8*16 ints
      if (tid < 128) s[tid] = src[(size_t)(blk * 8) * KNN + tid];
      __syncthreads();
      const int sub = tid & 127;   // float4 channel group
      const int ng = tid >> 7;     // 0..3
      const float4 bb = *(const float4*)&bias[sub * 4];
#pragma unroll
      for (int it = 0; it < 2; it++) {
        int nl = ng + it * 4;
        int n = blk * 8 + nl;
        float mx = -1e30f, my = -1e30f, mz = -1e30f, mw = -1e30f;
#pragma unroll
        for (int k = 0; k < KNN; k++) {
          int sa = s[nl * KNN + k];
          ushort4 u = *(const ushort4*)(PQb + (size_t)sa * 1024 + sub * 4);
          mx = fmaxf(mx, bf2f(u.x));
          my = fmaxf(my, bf2f(u.y));
          mz = fmaxf(mz, bf2f(u.z));
          mw = fmaxf(mw, bf2f(u.w));
        }
        const ushort* row = PQb + (size_t)n * 1024;
        ushort4 pu = *(const ushort4*)(row + sub * 4);
        ushort4 qu = *(const ushort4*)(row + 512 + sub * 4);
        float4 res;
        res.x = fmaxf(mx - bf2f(pu.x) + bf2f(qu.x) + bb.x, 0.f);
        res.y = fmaxf(my - bf2f(pu.y) + bf2f(qu.y) + bb.y, 0.f);
        res.z = fmaxf(mz - bf2f(pu.z) + bf2f(qu.z) + bb.z, 0.f);
        res.w = fmaxf(mw - bf2f(pu.w) + bf2f(qu.w) + bb.w, 0.f);
        *(float4*)(out + (size_t)n * OUT_STRIDE + out_off + sub * 4) = res;
        if (l < 2) {
          ushort4 pk;
          pk.x = f2bf(res.x);
          pk.y = f2bf(res.y);
          pk.z = f2bf(res.z);
          pk.w = f2bf(res.w);
          *(ushort4*)(Xb + (size_t)n * L_DIM + sub * 4) = pk;
        }
      }
    }

    if (l < 2) gbar(bar, ++gen * NBLK);
  }
}

extern "C" void kernel_launch(void* const* d_in, const int* in_sizes, int n_in,
                              void* d_out, int out_size, void* d_ws,
                              size_t ws_size, hipStream_t stream) {
  const float* rois = (const float*)d_in[0];
  const float* pooled = (const float*)d_in[1];
  const int* edge_index = (const int*)d_in[2];
  const float* gW1 = (const float*)d_in[3];
  const float* gb1 = (const float*)d_in[4];
  const float* gW2 = (const float*)d_in[5];
  const float* gb2 = (const float*)d_in[6];
  const float* fcW0 = (const float*)d_in[7];
  const float* fcb0 = (const float*)d_in[8];
  const float* fcW1 = (const float*)d_in[9];
  const float* fcb1 = (const float*)d_in[10];
  const float* fcW2 = (const float*)d_in[11];
  const float* fcb2 = (const float*)d_in[12];
  float* out = (float*)d_out;
  const int* src = edge_index;  // dst[e] == e/16 by construction

  // workspace layout (bytes):
  //   PQb : 4096*1024 bf16 = 8 MB  @ 0
  //   Xb  : 4096*512  bf16 = 4 MB  @ 8 MB  (stride IN_DIM for x0, L_DIM after)
  //   Wb0 : 1024*384  bf16         @ 12 MB
  //   Wb1 : 1024*512  bf16         @ 13 MB
  //   Wb2 : 1024*512  bf16         @ 14 MB
  //   bar : 64 B                   @ 16 MB
  char* ws = (char*)d_ws;
  ushort* PQb = (ushort*)ws;
  ushort* Xb = (ushort*)(ws + (size_t)8 * 1024 * 1024);
  ushort* Wb0 = (ushort*)(ws + (size_t)12 * 1024 * 1024);
  ushort* Wb1 = (ushort*)(ws + (size_t)13 * 1024 * 1024);
  ushort* Wb2 = (ushort*)(ws + (size_t)14 * 1024 * 1024);
  unsigned* bar = (unsigned*)(ws + (size_t)16 * 1024 * 1024);

  hipMemsetAsync(bar, 0, 64, stream);
  mega_kernel<<<NBLK, 512, 0, stream>>>(rois, pooled, gW1, gb1, gW2, gb2, fcW0,
                                        fcW1, fcW2, fcb0, fcb1, fcb2, src, out,
                                        Xb, Wb0, Wb1, Wb2, PQb, bar);
}

// Round 9
// 186.238 us; speedup vs baseline: 7.7563x; 4.2925x over previous
//
#include <hip/hip_runtime.h>
#include <hip/hip_bf16.h>

// Problem constants
#define BN_NODES 4096      // B*N = 8*512
#define KNN 16
#define C_POOL 256
#define G_DIM 128
#define IN_DIM 384         // C_POOL + G_DIM
#define L_DIM 512
#define OUT_STRIDE 1920    // 384 + 3*512

#define X1_OFF 384
#define X2_OFF 896
#define X3_OFF 1408

typedef __attribute__((ext_vector_type(8))) __bf16 bf16x8;
typedef __attribute__((ext_vector_type(4))) float floatx4;

static __device__ __forceinline__ ushort f2bf(float v) {
  return __builtin_bit_cast(ushort, __float2bfloat16(v));
}
static __device__ __forceinline__ float bf2f(ushort u) {
  return __builtin_bit_cast(float, ((unsigned)u) << 16);
}
static __device__ __forceinline__ void gld_lds(const ushort* g, ushort* l) {
  __builtin_amdgcn_global_load_lds(
      (const __attribute__((address_space(1))) void*)g,
      (__attribute__((address_space(3))) void*)l, 16, 0, 0);
}

// ---------------------------------------------------------------------------
// Kernel 1 (prep): blocks [0,512): node_feat (8 nodes/block);
//                  blocks [512,1920): wconv for all 3 layers.  (R6 verbatim)
// ---------------------------------------------------------------------------
__global__ __launch_bounds__(256) void prep_kernel(
    const float* __restrict__ rois, const float* __restrict__ pooled,
    const float* __restrict__ gW1, const float* __restrict__ gb1,
    const float* __restrict__ gW2, const float* __restrict__ gb2,
    const float* __restrict__ W0, const float* __restrict__ W1,
    const float* __restrict__ W2, float* __restrict__ out,
    ushort* __restrict__ Xb0, ushort* __restrict__ Wb0,
    ushort* __restrict__ Wb1, ushort* __restrict__ Wb2) {
  const int t = threadIdx.x;
  if (blockIdx.x >= 512) {
    int wi = blockIdx.x - 512;
    const float* W;
    ushort* Wb;
    int K, base;
    if (wi < 384) {
      W = W0; Wb = Wb0; K = IN_DIM; base = wi;
    } else if (wi < 896) {
      W = W1; Wb = Wb1; K = L_DIM; base = wi - 384;
    } else {
      W = W2; Wb = Wb2; K = L_DIM; base = wi - 896;
    }
    int elem = base * 1024 + t * 4;
    int j = elem / K;
    int k = elem - j * K;
    const float* srcp = (j < 512) ? W + (size_t)j * (2 * K) + k
                                  : W + (size_t)(j - 512) * (2 * K) + K + k;
    ushort4 pk;
    pk.x = f2bf(srcp[0]);
    pk.y = f2bf(srcp[1]);
    pk.z = f2bf(srcp[2]);
    pk.w = f2bf(srcp[3]);
    *(ushort4*)(Wb + (size_t)j * K + k) = pk;
    return;
  }
  const int nb = blockIdx.x * 8;
  const int c = t & 127;
  const int nh = t >> 7;
  __shared__ float rs[8 * 7];
  __shared__ __align__(16) float h1[8][G_DIM];
  if (t < 56) rs[t] = rois[(size_t)nb * 7 + t];
  __syncthreads();
  {
    float w1[7];
#pragma unroll
    for (int i = 0; i < 7; i++) w1[i] = gW1[c * 7 + i];
    float b1 = gb1[c];
#pragma unroll
    for (int n = nh * 4; n < nh * 4 + 4; n++) {
      float a = b1;
#pragma unroll
      for (int i = 0; i < 7; i++) a += rs[n * 7 + i] * w1[i];
      h1[n][c] = fmaxf(a, 0.f);
    }
  }
  __syncthreads();
  float acc[4];
  {
    float b2 = gb2[c];
#pragma unroll
    for (int n = 0; n < 4; n++) acc[n] = b2;
    const float4* w4 = (const float4*)(gW2 + (size_t)c * G_DIM);
#pragma unroll 4
    for (int kc = 0; kc < G_DIM / 4; kc++) {
      float4 wv = w4[kc];
#pragma unroll
      for (int n = 0; n < 4; n++) {
        float4 hv = ((const float4*)h1[nh * 4 + n])[kc];
        acc[n] += wv.x * hv.x + wv.y * hv.y + wv.z * hv.z + wv.w * hv.w;
      }
    }
  }
#pragma unroll
  for (int n = 0; n < 4; n++) {
    int node = nb + nh * 4 + n;
    float g = fmaxf(acc[n], 0.f);
    const float* prow = pooled + (size_t)node * C_POOL;
    float p0 = prow[c], p1 = prow[G_DIM + c];
    float* orow = out + (size_t)node * OUT_STRIDE;
    orow[c] = p0;
    orow[G_DIM + c] = p1;
    orow[C_POOL + c] = g;
    ushort* xrow = Xb0 + (size_t)node * IN_DIM;
    xrow[c] = f2bf(p0);
    xrow[G_DIM + c] = f2bf(p1);
    xrow[C_POOL + c] = f2bf(g);
  }
}

// ---------------------------------------------------------------------------
// Kernel 2: fused layer. Block = (stripe s 0..31, batch b 0..7) = 256 blocks.
// Stripe = 16 output channels: B-rows {s*16.. } (P) and {512+s*16.. } (Q).
// GEMM: sPQ[512 nodes x 32ch] = X_b[512 x K] @ Bstripe[32 x K]^T entirely
// in-LDS, then edge max+relu from sPQ. 512 threads = 8 waves (2/SIMD).
// LDS: sA dbuf 2x32 KB + sB 32 KB + sPQ 36 KB (row padded to 36 ushorts ->
// epilogue quads hit disjoint bank octets) = 132 KB, 1 block/CU.
// A-chunk = 256 rows x 64 k staged fragment-order; pipeline: sync -> stage
// next chunk -> compute current (stage latency overlaps compute).
// ---------------------------------------------------------------------------
__global__ __launch_bounds__(512, 2) void layer_kernel(
    const ushort* __restrict__ Xin, int ldx, int K,
    const ushort* __restrict__ Wb, const int* __restrict__ src,
    const float* __restrict__ bias, float* __restrict__ out, int out_off,
    ushort* __restrict__ Xout, int write_x) {
  __shared__ __align__(16) ushort sA[2][16384];  // 2 x 32 KB (32 tiles each)
  __shared__ __align__(16) ushort sB[16384];     // 32 KB (up to 32 tiles)
  __shared__ __align__(16) ushort sPQ[512 * 36]; // 36 KB
  const int s = blockIdx.x;
  const int b = blockIdx.y;
  const int tid = threadIdx.x;
  const int lane = tid & 63;
  const int w = tid >> 6;        // wave 0..7
  const int fr = lane & 15;
  const int kc = lane >> 4;

  const ushort* Ab = Xin + (size_t)(b * 512) * ldx;
  const int nk = K >> 6;         // 6 or 8 k0-steps
  const int nc = nk * 2;         // chunks (256 rows x 64 k)

  // ---- stage B stripe: tiles tb = kt*2 + ct, ct0 = P rows, ct1 = Q rows ----
  {
    int nbt = (K >> 5) * 2;      // 24 or 32 tiles
    for (int r = 0; r < nbt / 8; r++) {
      int tb = w + 8 * r;        // wave-uniform
      int kt = tb >> 1, ct = tb & 1;
      const ushort* g =
          Wb + (size_t)(ct * 512 + s * 16 + fr) * K + kt * 32 + kc * 8;
      gld_lds(g, &sB[tb * 512 + lane * 8]);
    }
  }
  // ---- stage A chunk 0 (rows 0..255, k 0..63): 32 tiles ta = rt*2 + ks ----
#pragma unroll
  for (int r = 0; r < 4; r++) {
    int ta = w * 4 + r;          // wave-uniform
    int rt = ta >> 1, ks = ta & 1;
    const ushort* g = Ab + (size_t)(rt * 16 + fr) * ldx + ks * 32 + kc * 8;
    gld_lds(g, &sA[0][ta * 512 + lane * 8]);
  }
  __syncthreads();

  floatx4 acc[4][2];             // [rb*2 + i][ct]
#pragma unroll
  for (int i = 0; i < 4; i++)
#pragma unroll
    for (int j = 0; j < 2; j++) acc[i][j] = (floatx4){0.f, 0.f, 0.f, 0.f};

  int c = 0;
  for (int k0i = 0; k0i < nk; k0i++) {
    bf16x8 bf[2][2];             // [ct][ks]
#pragma unroll
    for (int ks = 0; ks < 2; ks++)
#pragma unroll
      for (int ct = 0; ct < 2; ct++)
        bf[ct][ks] =
            *(const bf16x8*)&sB[((k0i * 2 + ks) * 2 + ct) * 512 + lane * 8];
#pragma unroll
    for (int rb = 0; rb < 2; rb++, c++) {
      const ushort* cur = sA[c & 1];
      // prefetch next chunk into other buffer (overlaps compute below)
      if (c + 1 < nc) {
        int k0n = (c + 1) >> 1, rbn = (c + 1) & 1;
        ushort* nxt = sA[(c + 1) & 1];
#pragma unroll
        for (int r = 0; r < 4; r++) {
          int ta = w * 4 + r;
          int rt = ta >> 1, ks = ta & 1;
          const ushort* g = Ab + (size_t)(rbn * 256 + rt * 16 + fr) * ldx +
                            k0n * 64 + ks * 32 + kc * 8;
          gld_lds(g, &nxt[ta * 512 + lane * 8]);
        }
      }
      // compute current chunk: wave w owns row-tiles 2w, 2w+1 (of 16)
#pragma unroll
      for (int i = 0; i < 2; i++) {
#pragma unroll
        for (int ks = 0; ks < 2; ks++) {
          bf16x8 av =
              *(const bf16x8*)&cur[((2 * w + i) * 2 + ks) * 512 + lane * 8];
#pragma unroll
          for (int ct = 0; ct < 2; ct++)
            acc[rb * 2 + i][ct] = __builtin_amdgcn_mfma_f32_16x16x32_bf16(
                av, bf[ct][ks], acc[rb * 2 + i][ct], 0, 0, 0);
        }
      }
      __syncthreads();  // drains prefetch; protects buffer for next overwrite
    }
  }

  // ---- epilogue: acc -> sPQ (C/D: col=fr, row=kc*4+reg; row pad 36) ----
#pragma unroll
  for (int rb = 0; rb < 2; rb++)
#pragma unroll
    for (int i = 0; i < 2; i++)
#pragma unroll
      for (int ct = 0; ct < 2; ct++)
#pragma unroll
        for (int r = 0; r < 4; r++)
          sPQ[(rb * 256 + (2 * w + i) * 16 + kc * 4 + r) * 36 + ct * 16 + fr] =
              f2bf(acc[rb * 2 + i][ct][r]);
  __syncthreads();

  // ---- edge phase: thread = node n (512 threads), 16 channels each ----
  {
    const int n = tid;
    const int* sp = src + (size_t)(b * 512 + n) * KNN;
    int nbr[KNN];
#pragma unroll
    for (int k4 = 0; k4 < 4; k4++) {
      int4 v = ((const int4*)sp)[k4];
      nbr[k4 * 4 + 0] = v.x - b * 512;
      nbr[k4 * 4 + 1] = v.y - b * 512;
      nbr[k4 * 4 + 2] = v.z - b * 512;
      nbr[k4 * 4 + 3] = v.w - b * 512;
    }
    float m[16];
#pragma unroll
    for (int c4 = 0; c4 < 16; c4++) m[c4] = -1e30f;
#pragma unroll
    for (int k = 0; k < KNN; k++) {
      const ushort* prow = &sPQ[nbr[k] * 36];
#pragma unroll
      for (int c4 = 0; c4 < 4; c4++) {
        ushort4 u = *(const ushort4*)(prow + c4 * 4);
        m[c4 * 4 + 0] = fmaxf(m[c4 * 4 + 0], bf2f(u.x));
        m[c4 * 4 + 1] = fmaxf(m[c4 * 4 + 1], bf2f(u.y));
        m[c4 * 4 + 2] = fmaxf(m[c4 * 4 + 2], bf2f(u.z));
        m[c4 * 4 + 3] = fmaxf(m[c4 * 4 + 3], bf2f(u.w));
      }
    }
    const ushort* own = &sPQ[n * 36];
    float* orow = out + (size_t)(b * 512 + n) * OUT_STRIDE + out_off + s * 16;
    ushort* xrow = Xout + (size_t)(b * 512 + n) * L_DIM + s * 16;
#pragma unroll
    for (int c4 = 0; c4 < 4; c4++) {
      ushort4 pu = *(const ushort4*)(own + c4 * 4);
      ushort4 qu = *(const ushort4*)(own + 16 + c4 * 4);
      float4 bb = *(const float4*)&bias[s * 16 + c4 * 4];
      float4 res;
      res.x = fmaxf(m[c4 * 4 + 0] - bf2f(pu.x) + bf2f(qu.x) + bb.x, 0.f);
      res.y = fmaxf(m[c4 * 4 + 1] - bf2f(pu.y) + bf2f(qu.y) + bb.y, 0.f);
      res.z = fmaxf(m[c4 * 4 + 2] - bf2f(pu.z) + bf2f(qu.z) + bb.z, 0.f);
      res.w = fmaxf(m[c4 * 4 + 3] - bf2f(pu.w) + bf2f(qu.w) + bb.w, 0.f);
      *(float4*)(orow + c4 * 4) = res;
      if (write_x) {
        ushort4 pk;
        pk.x = f2bf(res.x);
        pk.y = f2bf(res.y);
        pk.z = f2bf(res.z);
        pk.w = f2bf(res.w);
        *(ushort4*)(xrow + c4 * 4) = pk;
      }
    }
  }
}

extern "C" void kernel_launch(void* const* d_in, const int* in_sizes, int n_in,
                              void* d_out, int out_size, void* d_ws,
                              size_t ws_size, hipStream_t stream) {
  const float* rois = (const float*)d_in[0];
  const float* pooled = (const float*)d_in[1];
  const int* edge_index = (const int*)d_in[2];
  const float* gW1 = (const float*)d_in[3];
  const float* gb1 = (const float*)d_in[4];
  const float* gW2 = (const float*)d_in[5];
  const float* gb2 = (const float*)d_in[6];
  const float* fcW[3] = {(const float*)d_in[7], (const float*)d_in[9],
                         (const float*)d_in[11]};
  const float* fcb[3] = {(const float*)d_in[8], (const float*)d_in[10],
                         (const float*)d_in[12]};
  float* out = (float*)d_out;
  const int* src = edge_index;  // dst[e] == e/16 by construction

  // workspace layout (bytes):
  //   Xb0 : 4096*384 bf16 = 3 MB   @ 0
  //   Xb1 : 4096*512 bf16 = 4 MB   @ 4 MB
  //   Xb2 : 4096*512 bf16 = 4 MB   @ 8 MB
  //   Wb0 : 1024*384 bf16          @ 12 MB
  //   Wb1 : 1024*512 bf16          @ 13 MB
  //   Wb2 : 1024*512 bf16          @ 14 MB
  char* ws = (char*)d_ws;
  ushort* Xb0 = (ushort*)ws;
  ushort* Xb1 = (ushort*)(ws + (size_t)4 * 1024 * 1024);
  ushort* Xb2 = (ushort*)(ws + (size_t)8 * 1024 * 1024);
  ushort* Wb0 = (ushort*)(ws + (size_t)12 * 1024 * 1024);
  ushort* Wb1 = (ushort*)(ws + (size_t)13 * 1024 * 1024);
  ushort* Wb2 = (ushort*)(ws + (size_t)14 * 1024 * 1024);

  prep_kernel<<<1920, 256, 0, stream>>>(rois, pooled, gW1, gb1, gW2, gb2,
                                        fcW[0], fcW[1], fcW[2], out, Xb0, Wb0,
                                        Wb1, Wb2);
  layer_kernel<<<dim3(32, 8), 512, 0, stream>>>(Xb0, IN_DIM, IN_DIM, Wb0, src,
                                                fcb[0], out, X1_OFF, Xb1, 1);
  layer_kernel<<<dim3(32, 8), 512, 0, stream>>>(Xb1, L_DIM, L_DIM, Wb1, src,
                                                fcb[1], out, X2_OFF, Xb2, 1);
  layer_kernel<<<dim3(32, 8), 512, 0, stream>>>(Xb2, L_DIM, L_DIM, Wb2, src,
                                                fcb[2], out, X3_OFF, Xb2, 0);
}